// Round 2
// baseline (914.646 us; speedup 1.0000x reference)
//
#include <hip/hip_runtime.h>

typedef unsigned short u16;
typedef unsigned int u32;
typedef unsigned long long u64;

#define HW 16384

// ws float offsets (weights preconverted to fp32)
#define W_RED_WT  0        // [256][128]  wt[c][o]
#define W_RED_B   32768    // [128]
#define W_C1_WT   32896    // [128][32]
#define W_C1_B    36992    // [32]
#define W_C2_WT   37024    // [288][200]  wt[tap][o], tap = c*9+dy*3+dx
#define W_C2_B    94624    // [200]
#define W_EMB_WT  94824    // [256][32]
#define W_EMB_B   103016   // [32]
#define W_OUT_WT  103048   // [128][64]
#define W_OUT_B   111240   // [64]
#define W_BN_SC   111304   // [64]
#define W_BN_SH   111368   // [64]

#define FLAG_BYTE_OFF 446464   // u32 mode flag (after weights, before cat2)

// ws byte offsets for bf16 intermediates
#define CAT2_OFF  524288                      // [8][128][128][128] bf16
#define MIX_OFF   (CAT2_OFF + 33554432)       // [8][32][128][128]  bf16
#define WGT_OFF   (MIX_OFF + 8388608)         // [8][200][128][128] bf16

__device__ __forceinline__ float bf2f(u16 x) {
    u32 u = ((u32)x) << 16;
    float f; __builtin_memcpy(&f, &u, 4); return f;
}
__device__ __forceinline__ u16 f2bf(float f) {
    u32 u; __builtin_memcpy(&u, &f, 4);
    u32 r = (u + 0x7fffu + ((u >> 16) & 1u)) >> 16;
    return (u16)r;
}
__device__ __forceinline__ float lrelu(float x) { return x > 0.f ? x : 0.01f * x; }

// M=0: inputs/outputs are float32; M=1: bf16
template<int M>
__device__ __forceinline__ float ldin(const void* p, size_t i) {
    if (M == 0) return ((const float*)p)[i];
    return bf2f(((const u16*)p)[i]);
}
template<int M>
__device__ __forceinline__ void stout(void* p, size_t i, float v) {
    if (M == 0) ((float*)p)[i] = v;
    else ((u16*)p)[i] = f2bf(v);
}

// ---------------- dtype detector: sample even-index u16s of emb ----------------
__global__ void detect_kernel(const void* __restrict__ emb, u32* __restrict__ flag) {
    int tid = threadIdx.x;  // 64 threads
    const u16* p = (const u16*)emb;
    int e = (p[tid * 2] >> 7) & 0xFF;
    int ok = (e >= 100 && e <= 140) ? 1 : 0;
    u64 m = __ballot(ok);
    if (tid == 0) *flag = (__popcll(m) >= 32) ? 1u : 0u;
}

// ---------------- prep: convert weights to fp32 in ws ----------------
template<int M>
__global__ __launch_bounds__(256) void prep_kernel(
    const void* __restrict__ rw, const void* __restrict__ rb,
    const void* __restrict__ c1w, const void* __restrict__ c1b,
    const void* __restrict__ c2w, const void* __restrict__ c2b,
    const void* __restrict__ ew, const void* __restrict__ eb,
    const void* __restrict__ ow, const void* __restrict__ ob,
    const void* __restrict__ gam, const void* __restrict__ bet,
    const void* __restrict__ mn, const void* __restrict__ vr,
    float* __restrict__ o, const u32* __restrict__ flag)
{
    if (*flag != (u32)M) return;
    int i = blockIdx.x * 256 + threadIdx.x;
    if (i < 32768) { int c = i >> 7, oo = i & 127; o[W_RED_WT + i] = ldin<M>(rw, oo * 256 + c); }
    else if (i < 32896) { o[i] = ldin<M>(rb, i - 32768); }
    else if (i < 36992) { int j = i - 32896; int c = j >> 5, oo = j & 31; o[i] = ldin<M>(c1w, oo * 128 + c); }
    else if (i < 37024) { o[i] = ldin<M>(c1b, i - 36992); }
    else if (i < 94624) { int j = i - 37024; int tap = j / 200, oo = j - tap * 200; o[i] = ldin<M>(c2w, oo * 288 + tap); }
    else if (i < 94824) { o[i] = ldin<M>(c2b, i - 94624); }
    else if (i < 103016) { int j = i - 94824; int c = j >> 5, oo = j & 31; o[i] = ldin<M>(ew, oo * 256 + c); }
    else if (i < 103048) { o[i] = ldin<M>(eb, i - 103016); }
    else if (i < 111240) { int j = i - 103048; int c = j >> 6, oo = j & 63; o[i] = ldin<M>(ow, oo * 128 + c); }
    else if (i < 111304) { o[i] = ldin<M>(ob, i - 111240); }
    if (i < 64) {
        float sc = ldin<M>(gam, i) * rsqrtf(ldin<M>(vr, i) + 1e-5f);
        o[W_BN_SC + i] = sc;
        o[W_BN_SH + i] = ldin<M>(bet, i) - ldin<M>(mn, i) * sc;
    }
}

// ---------------- reduce: cat2 = 1x1 conv(concat(ps(hi), lo)) 256->128 ----------------
template<int M>
__global__ __launch_bounds__(256) void reduce_kernel(
    const void* __restrict__ hi, const void* __restrict__ lo,
    const float* __restrict__ wf, u16* __restrict__ cat2, const u32* __restrict__ flag)
{
    if (*flag != (u32)M) return;
    const int b = blockIdx.z, ocg = blockIdx.y;
    const int p0 = (blockIdx.x * 256 + threadIdx.x) * 2;
    const int h = p0 >> 7, w0 = p0 & 127;   // w0 even

    float acc0[16], acc1[16];
#pragma unroll
    for (int k = 0; k < 16; k++) { float bb = wf[W_RED_B + ocg * 16 + k]; acc0[k] = bb; acc1[k] = bb; }

    // pixel_shuffle: ps[b,c,h,w] = hi[b, c*4 + (h&1)*2 + (w&1), h/2, w/2]
    size_t hb = (size_t)b * 524288 + (size_t)((h & 1) * 2) * 4096 + (size_t)(h >> 1) * 64 + (size_t)(w0 >> 1);
#pragma unroll 4
    for (int c = 0; c < 32; c++) {
        float x0 = ldin<M>(hi, hb + (size_t)c * 16384);
        float x1 = ldin<M>(hi, hb + (size_t)c * 16384 + 4096);
#pragma unroll
        for (int k = 0; k < 16; k++) {
            float wv = wf[W_RED_WT + c * 128 + ocg * 16 + k];
            acc0[k] += wv * x0; acc1[k] += wv * x1;
        }
    }
    size_t lb = (size_t)b * 224 * HW + (size_t)h * 128 + (size_t)w0;
#pragma unroll 4
    for (int c = 0; c < 224; c++) {
        float x0 = ldin<M>(lo, lb + (size_t)c * HW);
        float x1 = ldin<M>(lo, lb + (size_t)c * HW + 1);
#pragma unroll
        for (int k = 0; k < 16; k++) {
            float wv = wf[W_RED_WT + (32 + c) * 128 + ocg * 16 + k];
            acc0[k] += wv * x0; acc1[k] += wv * x1;
        }
    }
    u16* op = cat2 + ((size_t)(b * 128 + ocg * 16)) * HW + p0;
#pragma unroll
    for (int k = 0; k < 16; k++) {
        u32 pair = (u32)f2bf(acc0[k]) | ((u32)f2bf(acc1[k]) << 16);
        *(u32*)(op + (size_t)k * HW) = pair;
    }
}

// ---------------- mix = lrelu(conv1(cat2) + embconv(emb)) ----------------
template<int M>
__global__ __launch_bounds__(256) void mix_kernel(
    const u16* __restrict__ cat2, const void* __restrict__ emb,
    const float* __restrict__ wf, u16* __restrict__ mix, const u32* __restrict__ flag)
{
    if (*flag != (u32)M) return;
    const int b = blockIdx.y;
    const int p0 = (blockIdx.x * 256 + threadIdx.x) * 2;

    float a0[32], a1[32];
#pragma unroll
    for (int o = 0; o < 32; o++) { float bb = wf[W_C1_B + o] + wf[W_EMB_B + o]; a0[o] = bb; a1[o] = bb; }

    const u32* cb = (const u32*)(cat2 + (size_t)b * 128 * HW + p0);
#pragma unroll 2
    for (int c = 0; c < 128; c++) {
        u32 v = cb[(size_t)c * 8192];
        float x0 = bf2f((u16)v), x1 = bf2f((u16)(v >> 16));
#pragma unroll
        for (int o = 0; o < 32; o++) {
            float wv = wf[W_C1_WT + c * 32 + o];
            a0[o] += wv * x0; a1[o] += wv * x1;
        }
    }
    size_t eb = (size_t)b * 256 * HW + (size_t)p0;
#pragma unroll 2
    for (int c = 0; c < 256; c++) {
        float x0 = ldin<M>(emb, eb + (size_t)c * HW);
        float x1 = ldin<M>(emb, eb + (size_t)c * HW + 1);
#pragma unroll
        for (int o = 0; o < 32; o++) {
            float wv = wf[W_EMB_WT + c * 32 + o];
            a0[o] += wv * x0; a1[o] += wv * x1;
        }
    }
    u16* op = mix + (size_t)b * 32 * HW + p0;
#pragma unroll
    for (int o = 0; o < 32; o++) {
        u32 pair = (u32)f2bf(lrelu(a0[o])) | ((u32)f2bf(lrelu(a1[o])) << 16);
        *(u32*)(op + (size_t)o * HW) = pair;
    }
}

// ---------------- conv2: 3x3, 32->200, pad 1 (mode-independent: ws only) ----------------
__global__ __launch_bounds__(256) void conv2_kernel(
    const u16* __restrict__ mix, const float* __restrict__ wf, u16* __restrict__ wgt)
{
    const int b = blockIdx.z, ocg = blockIdx.y;
    const int th = (blockIdx.x >> 3) * 16, tw = (blockIdx.x & 7) * 16;
    const int tid = threadIdx.x, ty = tid >> 4, tx = tid & 15;

    __shared__ u16 lds[32 * 324];   // [c][18][18]
    for (int idx = tid; idx < 10368; idx += 256) {
        int c = idx / 324, r = idx - c * 324;
        int yy = r / 18, xx = r - yy * 18;
        int hh = th + yy - 1, ww = tw + xx - 1;
        u16 v = 0;
        if (hh >= 0 && hh < 128 && ww >= 0 && ww < 128)
            v = mix[((size_t)(b * 32 + c)) * HW + hh * 128 + ww];
        lds[idx] = v;
    }
    __syncthreads();

    float acc[25];
#pragma unroll
    for (int o = 0; o < 25; o++) acc[o] = wf[W_C2_B + ocg * 25 + o];

#pragma unroll 1
    for (int c = 0; c < 32; c++) {
#pragma unroll
        for (int dy = 0; dy < 3; dy++) {
#pragma unroll
            for (int dx = 0; dx < 3; dx++) {
                float xv = bf2f(lds[c * 324 + (ty + dy) * 18 + tx + dx]);
                const float* wp = wf + W_C2_WT + (c * 9 + dy * 3 + dx) * 200 + ocg * 25;
#pragma unroll
                for (int o = 0; o < 25; o++) acc[o] += wp[o] * xv;
            }
        }
    }
    const int h = th + ty, w = tw + tx;
#pragma unroll
    for (int o = 0; o < 25; o++)
        wgt[((size_t)(b * 200 + ocg * 25 + o)) * HW + h * 128 + w] = f2bf(acc[o]);
}

// ---------------- involution (K=5, g=8) + 1x1 out conv + BN + lrelu ----------------
template<int M>
__global__ __launch_bounds__(256) void inv_out_kernel(
    const u16* __restrict__ cat2, const u16* __restrict__ wgt,
    const float* __restrict__ wf, void* __restrict__ out, const u32* __restrict__ flag)
{
    if (*flag != (u32)M) return;
    const int b = blockIdx.y;
    const int th = (blockIdx.x >> 3) * 16, tw = (blockIdx.x & 7) * 16;
    const int tid = threadIdx.x, ty = tid >> 4, tx = tid & 15;
    const int h = th + ty, w = tw + tx;

    __shared__ u16 lds[16 * 400];   // [c][20][20]
    float acc[64];
#pragma unroll
    for (int oc = 0; oc < 64; oc++) acc[oc] = wf[W_OUT_B + oc];

#pragma unroll 1
    for (int g = 0; g < 8; g++) {
        __syncthreads();
        for (int idx = tid; idx < 6400; idx += 256) {
            int c = idx / 400, r = idx - c * 400;
            int yy = r / 20, xx = r - yy * 20;
            int hh = th + yy - 2, ww = tw + xx - 2;
            u16 v = 0;
            if (hh >= 0 && hh < 128 && ww >= 0 && ww < 128)
                v = cat2[((size_t)(b * 128 + g * 16 + c)) * HW + hh * 128 + ww];
            lds[idx] = v;
        }
        __syncthreads();

        float wv[25];
#pragma unroll
        for (int ij = 0; ij < 25; ij++)
            wv[ij] = bf2f(wgt[((size_t)(b * 200 + g * 25 + ij)) * HW + h * 128 + w]);

#pragma unroll 1
        for (int c = 0; c < 16; c++) {
            float s = 0.f;
#pragma unroll
            for (int i = 0; i < 5; i++)
#pragma unroll
                for (int j = 0; j < 5; j++)
                    s += wv[i * 5 + j] * bf2f(lds[c * 400 + (ty + i) * 20 + tx + j]);
            const float* wp = wf + W_OUT_WT + (g * 16 + c) * 64;
#pragma unroll
            for (int oc = 0; oc < 64; oc++) acc[oc] += wp[oc] * s;
        }
    }
#pragma unroll
    for (int oc = 0; oc < 64; oc++) {
        float y = acc[oc] * wf[W_BN_SC + oc] + wf[W_BN_SH + oc];
        stout<M>(out, ((size_t)(b * 64 + oc)) * HW + (size_t)(h * 128 + w), lrelu(y));
    }
}

extern "C" void kernel_launch(void* const* d_in, const int* in_sizes, int n_in,
                              void* d_out, int out_size, void* d_ws, size_t ws_size,
                              hipStream_t stream) {
    const void* hi  = d_in[0];
    const void* lo  = d_in[1];
    const void* emb = d_in[2];

    float* wsf = (float*)d_ws;
    u32* flag = (u32*)((char*)d_ws + FLAG_BYTE_OFF);
    u16* cat2 = (u16*)((char*)d_ws + CAT2_OFF);
    u16* mix  = (u16*)((char*)d_ws + MIX_OFF);
    u16* wgt  = (u16*)((char*)d_ws + WGT_OFF);

    detect_kernel<<<1, 64, 0, stream>>>(emb, flag);

    prep_kernel<0><<<435, 256, 0, stream>>>(
        d_in[3], d_in[4], d_in[5], d_in[6], d_in[7], d_in[8], d_in[9], d_in[10],
        d_in[11], d_in[12], d_in[13], d_in[14], d_in[15], d_in[16], wsf, flag);
    prep_kernel<1><<<435, 256, 0, stream>>>(
        d_in[3], d_in[4], d_in[5], d_in[6], d_in[7], d_in[8], d_in[9], d_in[10],
        d_in[11], d_in[12], d_in[13], d_in[14], d_in[15], d_in[16], wsf, flag);

    reduce_kernel<0><<<dim3(32, 8, 8), 256, 0, stream>>>(hi, lo, wsf, cat2, flag);
    reduce_kernel<1><<<dim3(32, 8, 8), 256, 0, stream>>>(hi, lo, wsf, cat2, flag);

    mix_kernel<0><<<dim3(32, 8), 256, 0, stream>>>(cat2, emb, wsf, mix, flag);
    mix_kernel<1><<<dim3(32, 8), 256, 0, stream>>>(cat2, emb, wsf, mix, flag);

    conv2_kernel<<<dim3(64, 8, 8), 256, 0, stream>>>(mix, wsf, wgt);

    inv_out_kernel<0><<<dim3(64, 8), 256, 0, stream>>>(cat2, wgt, wsf, d_out, flag);
    inv_out_kernel<1><<<dim3(64, 8), 256, 0, stream>>>(cat2, wgt, wsf, d_out, flag);
}

// Round 3
// 488.070 us; speedup vs baseline: 1.8740x; 1.8740x over previous
//
#include <hip/hip_runtime.h>

typedef unsigned short u16; typedef unsigned int u32; typedef unsigned long long u64;
typedef __attribute__((ext_vector_type(8))) short short8;
typedef __attribute__((ext_vector_type(16))) float f32x16;

#define HW 16384

// fp32 ws region (float index)
#define RED_B  0
#define C1E_B  128
#define C2_B   160
#define OUT_B  416
#define BN_SC  480
#define BN_SH  544
// byte offsets in ws
#define FLAG_OFF   4096
#define RWB_OFF    8192      // bf16 [128][256]
#define C1B_OFF    73728     // bf16 [32][128]
#define EMBB_OFF   81920     // bf16 [32][256]
#define OUTB_OFF   98304     // bf16 [64][128]
#define C2PB_OFF   114688    // bf16 [256][288] tap-major (k' = tap*32+ic), rows>=200 zero
#define CAT2_OFF   524288    // bf16 [8*16384][128] pixel-major
#define MIX_OFF    34078720  // bf16 [8*16384][32]  pixel-major
#define WGT_OFF    42467328  // bf16 [8][200][16384] channel-major

__device__ __forceinline__ float bf2f(u16 x){ u32 u=((u32)x)<<16; float f; __builtin_memcpy(&f,&u,4); return f; }
__device__ __forceinline__ u16 f2bf(float f){ u32 u; __builtin_memcpy(&u,&f,4); return (u16)((u + 0x7fffu + ((u>>16)&1u))>>16); }
__device__ __forceinline__ float lrelu(float x){ return x>0.f ? x : 0.01f*x; }

template<int M> __device__ __forceinline__ u16 ldb(const void* p, size_t i){
    if (M==1) return ((const u16*)p)[i];
    return f2bf(((const float*)p)[i]);
}
template<int M> __device__ __forceinline__ float ldf(const void* p, size_t i){
    if (M==1) return bf2f(((const u16*)p)[i]);
    return ((const float*)p)[i];
}
// swizzled A-tile store: stride in u16 units, chunk XOR to decorrelate banks
__device__ __forceinline__ void stA(u16* At, int stride, int p, int c, u16 v){
    At[p*stride + ((((c>>3) ^ ((p>>1)&7)))<<3) + (c&7)] = v;
}

// ---------------- dtype detector ----------------
__global__ void detect_kernel(const void* __restrict__ emb, u32* __restrict__ flag){
    int tid = threadIdx.x;
    const u16* p = (const u16*)emb;
    int e = (p[tid*2] >> 7) & 0xFF;
    u64 m = __ballot(e >= 100 && e <= 140);
    if (tid == 0) *flag = (__popcll(m) >= 32) ? 1u : 0u;
}

// ---------------- prep: weights -> fp32 biases + bf16 MFMA operands ----------------
template<int M>
__global__ __launch_bounds__(256) void k_prep(
    const void* rw, const void* rb, const void* c1w, const void* c1b,
    const void* c2w, const void* c2b, const void* ew, const void* eb,
    const void* ow, const void* ob, const void* gam, const void* bet,
    const void* mn, const void* vr, char* ws, const u32* flag)
{
    if (*flag != (u32)M) return;
    float* wf = (float*)ws;
    int i = blockIdx.x*256 + threadIdx.x;
    if (i < 32768)       ((u16*)(ws+RWB_OFF))[i] = ldb<M>(rw, i);
    else if (i < 36864)  ((u16*)(ws+C1B_OFF))[i-32768] = ldb<M>(c1w, i-32768);
    else if (i < 45056)  ((u16*)(ws+EMBB_OFF))[i-36864] = ldb<M>(ew, i-36864);
    else if (i < 53248)  ((u16*)(ws+OUTB_OFF))[i-45056] = ldb<M>(ow, i-45056);
    else if (i < 126976) {
        int j = i-53248; int o = j/288, k = j - o*288;
        int tap = k>>5, ic = k&31;
        u16 v = 0;
        if (o < 200) v = ldb<M>(c2w, (size_t)o*288 + ic*9 + tap);
        ((u16*)(ws+C2PB_OFF))[j] = v;
    }
    else if (i < 127584) {
        int j = i-126976;
        if (j < 128) wf[RED_B+j] = ldf<M>(rb, j);
        else if (j < 160) wf[C1E_B+j-128] = ldf<M>(c1b, j-128) + ldf<M>(eb, j-128);
        else if (j < 416) { int o = j-160; wf[C2_B+o] = (o<200) ? ldf<M>(c2b,o) : 0.f; }
        else if (j < 480) wf[OUT_B+j-416] = ldf<M>(ob, j-416);
        else if (j < 544) { int c=j-480; wf[BN_SC+c] = ldf<M>(gam,c) * rsqrtf(ldf<M>(vr,c)+1e-5f); }
        else { int c=j-544; wf[BN_SH+c] = ldf<M>(bet,c) - ldf<M>(mn,c)*ldf<M>(gam,c)*rsqrtf(ldf<M>(vr,c)+1e-5f); }
    }
}

// ---------------- reduce: cat2[px][128] = W_red(256->128) @ concat(ps(hi), lo) ----------------
template<int M>
__global__ __launch_bounds__(256) void k_reduce(
    const void* __restrict__ hi, const void* __restrict__ lo,
    const u16* __restrict__ rwB, const float* __restrict__ wf,
    u16* __restrict__ cat2, const u32* __restrict__ flag)
{
    if (*flag != (u32)M) return;
    __shared__ u16 At[64*264];
    const int tid = threadIdx.x, wvi = tid>>6, lane = tid&63;
    const int rt = (wvi>>1)*32, nc0 = (wvi&1)*64;
    const int col = lane&31, q = lane>>5;

    short8 B[2][16];
#pragma unroll
    for (int nt=0; nt<2; nt++){
        int o = nc0 + nt*32 + col;
#pragma unroll
        for (int s=0; s<16; s++)
            __builtin_memcpy(&B[nt][s], rwB + (size_t)o*256 + s*16 + q*8, 16);
    }

    for (int it=0; it<4; it++){
        int chunk = blockIdx.x + it*512;
        int gpx = chunk*64;
        int b = gpx>>14, p0 = gpx&16383;
        int h = p0>>7, w0 = p0&127;
        __syncthreads();
        { // lo -> cat channels 32..255
            int qq = tid&31, cid = tid>>5;
#pragma unroll 4
            for (int i=0;i<28;i++){
                int c = cid*28 + i;
                size_t src = ((size_t)(b*224 + c))*HW + p0 + 2*qq;
                u16 v0, v1;
                if (M==1){ u32 v = *(const u32*)((const u16*)lo + src); v0=(u16)v; v1=(u16)(v>>16); }
                else { v0 = f2bf(((const float*)lo)[src]); v1 = f2bf(((const float*)lo)[src+1]); }
                stA(At,264, 2*qq,   32+c, v0);
                stA(At,264, 2*qq+1, 32+c, v1);
            }
        }
        { // hi pixel-shuffle -> cat channels 0..31
            int xq = tid&15, cid = tid>>4;
#pragma unroll
            for (int i=0;i<2;i++){
                int c = cid + i*16;
                int hc = c*4 + (h&1)*2;
                size_t src = ((size_t)(b*128 + hc))*4096 + (size_t)(h>>1)*64 + (w0>>1) + 2*xq;
                u16 e0 = ldb<M>(hi, src),      e1 = ldb<M>(hi, src+1);
                u16 o0 = ldb<M>(hi, src+4096), o1 = ldb<M>(hi, src+4097);
                stA(At,264, 4*xq,   c, e0);
                stA(At,264, 4*xq+2, c, e1);
                stA(At,264, 4*xq+1, c, o0);
                stA(At,264, 4*xq+3, c, o1);
            }
        }
        __syncthreads();

        f32x16 acc0, acc1;
#pragma unroll
        for (int r=0;r<16;r++){ acc0[r]=0.f; acc1[r]=0.f; }
        int pp = rt + col, sw = (pp>>1)&7;
        const u16* arow = At + pp*264;
#pragma unroll
        for (int s=0;s<16;s++){
            short8 a;
            __builtin_memcpy(&a, arow + (((2*s+q)^sw)<<3), 16);
            acc0 = __builtin_amdgcn_mfma_f32_32x32x16_bf16(a, B[0][s], acc0, 0,0,0);
            acc1 = __builtin_amdgcn_mfma_f32_32x32x16_bf16(a, B[1][s], acc1, 0,0,0);
        }
#pragma unroll
        for (int nt=0; nt<2; nt++){
            int oc = nc0 + nt*32 + col;
            float bias = wf[RED_B + oc];
#pragma unroll
            for (int r=0;r<16;r++){
                int row = (r&3) + 8*(r>>2) + 4*q;
                float v = (nt ? acc1[r] : acc0[r]) + bias;
                cat2[((size_t)(gpx + rt + row))*128 + oc] = f2bf(v);
            }
        }
    }
}

// ---------------- mix[px][32] = lrelu(conv1(cat2) + embconv(emb)) ----------------
template<int M>
__global__ __launch_bounds__(256) void k_mix(
    const u16* __restrict__ cat2, const void* __restrict__ emb,
    const u16* __restrict__ c1B, const u16* __restrict__ embB,
    const float* __restrict__ wf, u16* __restrict__ mixt, const u32* __restrict__ flag)
{
    if (*flag != (u32)M) return;
    __shared__ u16 At[128*136];
    const int tid = threadIdx.x, wvi = tid>>6, lane = tid&63;
    const int rt = wvi*32, col = lane&31, q = lane>>5;

    short8 Bc[8], Be[16];
#pragma unroll
    for (int s=0;s<8;s++)  __builtin_memcpy(&Bc[s], c1B  + (size_t)col*128 + s*16 + q*8, 16);
#pragma unroll
    for (int s=0;s<16;s++) __builtin_memcpy(&Be[s], embB + (size_t)col*256 + s*16 + q*8, 16);

    for (int it=0; it<4; it++){
        int chunk = blockIdx.x + it*256;
        int gpx = chunk*128;
        int b = gpx>>14, p0 = gpx&16383;

        f32x16 acc;
#pragma unroll
        for (int r=0;r<16;r++) acc[r]=0.f;
        int pp = rt + col, sw = (pp>>1)&7;
        const u16* arow = At + pp*136;

        // K phase 0: cat2 channels (direct swizzled copy)
        __syncthreads();
#pragma unroll
        for (int i=0;i<8;i++){
            int idx = tid + i*256;
            int p = idx>>4, c16 = idx&15;
            short8 v;
            __builtin_memcpy(&v, cat2 + ((size_t)(gpx+p))*128 + c16*8, 16);
            *(short8*)(At + p*136 + ((c16 ^ ((p>>1)&7))<<3)) = v;
        }
        __syncthreads();
#pragma unroll
        for (int s=0;s<8;s++){
            short8 a; __builtin_memcpy(&a, arow + (((2*s+q)^sw)<<3), 16);
            acc = __builtin_amdgcn_mfma_f32_32x32x16_bf16(a, Bc[s], acc, 0,0,0);
        }
        // K phases 1,2: emb channels (transposed staging)
#pragma unroll 1
        for (int half=0; half<2; half++){
            __syncthreads();
            {
                int qq = tid&31, cid = (tid>>5)&1, g2 = tid>>6;
#pragma unroll 2
                for (int ph=0; ph<2; ph++)
#pragma unroll 4
                for (int i=0;i<16;i++){
                    int c = cid*64 + g2*16 + i;
                    int ec = half*128 + c;
                    int p = ph*64 + 2*qq;
                    size_t src = ((size_t)(b*256 + ec))*HW + p0 + p;
                    u16 v0, v1;
                    if (M==1){ u32 v = *(const u32*)((const u16*)emb + src); v0=(u16)v; v1=(u16)(v>>16); }
                    else { v0 = f2bf(((const float*)emb)[src]); v1 = f2bf(((const float*)emb)[src+1]); }
                    stA(At,136, p,   c, v0);
                    stA(At,136, p+1, c, v1);
                }
            }
            __syncthreads();
#pragma unroll
            for (int s=0;s<8;s++){
                short8 a; __builtin_memcpy(&a, arow + (((2*s+q)^sw)<<3), 16);
                acc = __builtin_amdgcn_mfma_f32_32x32x16_bf16(a, Be[half*8+s], acc, 0,0,0);
            }
        }
        float bias = wf[C1E_B + col];
#pragma unroll
        for (int r=0;r<16;r++){
            int row = (r&3) + 8*(r>>2) + 4*q;
            mixt[((size_t)(gpx + rt + row))*32 + col] = f2bf(lrelu(acc[r] + bias));
        }
    }
}

// ---------------- conv2 (3x3, 32->200 pad to 256) as im2col GEMM K=288 ----------------
__global__ __launch_bounds__(256) void k_conv2(
    const u16* __restrict__ mixt, const u16* __restrict__ c2B,
    const float* __restrict__ wf, u16* __restrict__ wgt)
{
    __shared__ u16 halo[100*32];
    const int tid = threadIdx.x, wvi = tid>>6, lane = tid&63;
    const int rt = (wvi>>1)*32, npair = wvi&1;
    const int nh = blockIdx.x & 1;
    const int nc0 = nh*128 + npair*64;
    const int col = lane&31, q = lane>>5;

    short8 B[2][18];
#pragma unroll
    for (int nt=0; nt<2; nt++){
        int o = nc0 + nt*32 + col;
#pragma unroll
        for (int s=0; s<18; s++)
            __builtin_memcpy(&B[nt][s], c2B + (size_t)o*288 + s*16 + q*8, 16);
    }

    for (int it=0; it<4; it++){
        int tile = (blockIdx.x>>1) + it*512;
        int b = tile>>8, tl = tile&255;
        int ty = tl>>4, tx = tl&15;
        __syncthreads();
#pragma unroll
        for (int i=0;i<2;i++){
            int idx = tid + i*256;
            if (idx < 400){
                int point = idx>>2, cq = idx&3;
                int y = ty*8 + point/10 - 1, x = tx*8 + point%10 - 1;
                short8 v;
                if (y>=0 && y<128 && x>=0 && x<128)
                    __builtin_memcpy(&v, mixt + ((size_t)(b*HW + y*128 + x))*32 + cq*8, 16);
                else { short z = 0; v = (short8){z,z,z,z,z,z,z,z}; }
                *(short8*)(halo + point*32 + cq*8) = v;
            }
        }
        __syncthreads();

        f32x16 acc0, acc1;
#pragma unroll
        for (int r=0;r<16;r++){ acc0[r]=0.f; acc1[r]=0.f; }
        int pp = rt + col, py = pp>>3, px = pp&7;
#pragma unroll
        for (int s=0;s<18;s++){
            int tap = s>>1, ih = s&1;
            int dy = tap/3, dx = tap%3;
            short8 a;
            __builtin_memcpy(&a, halo + ((py+dy)*10 + px+dx)*32 + ih*16 + q*8, 16);
            acc0 = __builtin_amdgcn_mfma_f32_32x32x16_bf16(a, B[0][s], acc0, 0,0,0);
            acc1 = __builtin_amdgcn_mfma_f32_32x32x16_bf16(a, B[1][s], acc1, 0,0,0);
        }
#pragma unroll
        for (int nt=0; nt<2; nt++){
            int oc = nc0 + nt*32 + col;
            if (oc < 200){
                float bias = wf[C2_B + oc];
#pragma unroll
                for (int r=0;r<16;r++){
                    int row = (r&3) + 8*(r>>2) + 4*q;
                    int p2 = rt + row;
                    int y = ty*8 + (p2>>3), x = tx*8 + (p2&7);
                    float v = (nt ? acc1[r] : acc0[r]) + bias;
                    wgt[((size_t)(b*200 + oc))*HW + y*128 + x] = f2bf(v);
                }
            }
        }
    }
}

// ---------------- involution (K=5,g=8) + out conv (MFMA) + BN + lrelu ----------------
template<int M>
__global__ __launch_bounds__(256) void k_inv(
    const u16* __restrict__ cat2, const u16* __restrict__ wgt,
    const u16* __restrict__ outB, const float* __restrict__ wf,
    void* __restrict__ out, const u32* __restrict__ flag)
{
    if (*flag != (u32)M) return;
    __shared__ u16 halo[400*16];
    __shared__ u16 og[256*16];
    const int tid = threadIdx.x, wvi = tid>>6, lane = tid&63;
    const int col = lane&31, q = lane>>5;
    const int b = blockIdx.y, ty = blockIdx.x>>3, tx = blockIdx.x&7;
    const int py = tid>>4, px = tid&15;
    const int h = ty*16 + py, w = tx*16 + px;

    f32x16 acc[2][2];
#pragma unroll
    for (int i=0;i<2;i++)
#pragma unroll
    for (int j=0;j<2;j++)
#pragma unroll
    for (int r=0;r<16;r++) acc[i][j][r] = 0.f;

#pragma unroll 1
    for (int g=0; g<8; g++){
        __syncthreads();
#pragma unroll
        for (int i=0;i<4;i++){
            int idx = tid + i*256;
            if (idx < 800){
                int point = idx>>1, cq = idx&1;
                int y = ty*16 + point/20 - 2, x = tx*16 + point%20 - 2;
                short8 v;
                if (y>=0 && y<128 && x>=0 && x<128)
                    __builtin_memcpy(&v, cat2 + ((size_t)(b*HW + y*128 + x))*128 + g*16 + cq*8, 16);
                else { short z=0; v = (short8){z,z,z,z,z,z,z,z}; }
                *(short8*)(halo + point*16 + cq*8) = v;
            }
        }
        __syncthreads();

        float wvv[25];
#pragma unroll
        for (int t=0;t<25;t++)
            wvv[t] = bf2f(wgt[((size_t)(b*200 + g*25 + t))*HW + h*128 + w]);

        float a16[16];
#pragma unroll
        for (int cc=0;cc<16;cc++) a16[cc]=0.f;
#pragma unroll
        for (int t=0;t<25;t++){
            int dy = t/5, dx = t%5;
            u32 vv[8];
            __builtin_memcpy(vv, halo + ((py+dy)*20 + px+dx)*16, 32);
            float wt = wvv[t];
#pragma unroll
            for (int r=0;r<8;r++){
                u32 u = vv[r];
                u32 ulo = u<<16, uhi = u & 0xffff0000u;
                float x0, x1;
                __builtin_memcpy(&x0,&ulo,4); __builtin_memcpy(&x1,&uhi,4);
                a16[2*r]   += wt*x0;
                a16[2*r+1] += wt*x1;
            }
        }
        u32 pk[8];
#pragma unroll
        for (int r=0;r<8;r++) pk[r] = (u32)f2bf(a16[2*r]) | ((u32)f2bf(a16[2*r+1])<<16);
        __syncthreads();  // prior MFMA og reads complete
        __builtin_memcpy(og + tid*16, pk, 32);
        __syncthreads();

        short8 bo0, bo1;
        __builtin_memcpy(&bo0, outB + (size_t)(col)*128      + g*16 + q*8, 16);
        __builtin_memcpy(&bo1, outB + (size_t)(32+col)*128   + g*16 + q*8, 16);
#pragma unroll
        for (int rt2=0; rt2<2; rt2++){
            int prow = (wvi*2 + rt2)*32 + col;
            short8 a; __builtin_memcpy(&a, og + prow*16 + q*8, 16);
            acc[rt2][0] = __builtin_amdgcn_mfma_f32_32x32x16_bf16(a, bo0, acc[rt2][0], 0,0,0);
            acc[rt2][1] = __builtin_amdgcn_mfma_f32_32x32x16_bf16(a, bo1, acc[rt2][1], 0,0,0);
        }
    }
#pragma unroll
    for (int rt2=0; rt2<2; rt2++)
#pragma unroll
    for (int nt=0; nt<2; nt++){
        int oc = nt*32 + col;
        float bias = wf[OUT_B+oc], sc = wf[BN_SC+oc], sh = wf[BN_SH+oc];
#pragma unroll
        for (int r=0;r<16;r++){
            int row = (r&3) + 8*(r>>2) + 4*q;
            int p = (wvi*2 + rt2)*32 + row;
            int yy = ty*16 + (p>>4), xx = tx*16 + (p&15);
            float v = lrelu((acc[rt2][nt][r] + bias)*sc + sh);
            size_t oidx = ((size_t)(b*64 + oc))*HW + yy*128 + xx;
            if (M==1) ((u16*)out)[oidx] = f2bf(v);
            else ((float*)out)[oidx] = v;
        }
    }
}

extern "C" void kernel_launch(void* const* d_in, const int* in_sizes, int n_in,
                              void* d_out, int out_size, void* d_ws, size_t ws_size,
                              hipStream_t stream) {
    const void* hi  = d_in[0];
    const void* lo  = d_in[1];
    const void* emb = d_in[2];
    char* ws = (char*)d_ws;
    float* wf = (float*)ws;
    u32* flag = (u32*)(ws + FLAG_OFF);
    u16* cat2 = (u16*)(ws + CAT2_OFF);
    u16* mixt = (u16*)(ws + MIX_OFF);
    u16* wgt  = (u16*)(ws + WGT_OFF);

    detect_kernel<<<1, 64, 0, stream>>>(emb, flag);

    k_prep<0><<<499,256,0,stream>>>(d_in[3],d_in[4],d_in[5],d_in[6],d_in[7],d_in[8],
        d_in[9],d_in[10],d_in[11],d_in[12],d_in[13],d_in[14],d_in[15],d_in[16], ws, flag);
    k_prep<1><<<499,256,0,stream>>>(d_in[3],d_in[4],d_in[5],d_in[6],d_in[7],d_in[8],
        d_in[9],d_in[10],d_in[11],d_in[12],d_in[13],d_in[14],d_in[15],d_in[16], ws, flag);

    k_reduce<0><<<512,256,0,stream>>>(hi, lo, (const u16*)(ws+RWB_OFF), wf, cat2, flag);
    k_reduce<1><<<512,256,0,stream>>>(hi, lo, (const u16*)d_in[3],      wf, cat2, flag);

    k_mix<0><<<256,256,0,stream>>>(cat2, emb, (const u16*)(ws+C1B_OFF), (const u16*)(ws+EMBB_OFF), wf, mixt, flag);
    k_mix<1><<<256,256,0,stream>>>(cat2, emb, (const u16*)d_in[5],      (const u16*)d_in[9],       wf, mixt, flag);

    k_conv2<<<1024,256,0,stream>>>(mixt, (const u16*)(ws+C2PB_OFF), wf, wgt);

    k_inv<0><<<dim3(64,8),256,0,stream>>>(cat2, wgt, (const u16*)(ws+OUTB_OFF), wf, d_out, flag);
    k_inv<1><<<dim3(64,8),256,0,stream>>>(cat2, wgt, (const u16*)d_in[11],      wf, d_out, flag);
}

// Round 4
// 479.545 us; speedup vs baseline: 1.9073x; 1.0178x over previous
//
#include <hip/hip_runtime.h>

typedef unsigned short u16; typedef unsigned int u32; typedef unsigned long long u64;
typedef __attribute__((ext_vector_type(8))) short short8;
typedef __attribute__((ext_vector_type(16))) float f32x16;

#define HW 16384

// fp32 ws region (float index)
#define RED_B  0
#define C1E_B  128
#define C2_B   160
#define OUT_B  416
#define BN_SC  480
#define BN_SH  544
// byte offsets in ws
#define FLAG_OFF   4096
#define RWB_OFF    8192      // bf16 [128][256]
#define C1B_OFF    73728     // bf16 [32][128]
#define EMBB_OFF   81920     // bf16 [32][256]
#define OUTB_OFF   98304     // bf16 [64][128]
#define C2PB_OFF   114688    // bf16 [256][288] tap-major
#define CAT2_OFF   524288    // bf16 [8*16384][128] pixel-major
#define MIX_OFF    34078720  // bf16 [8*16384][32]  pixel-major
#define WGT_OFF    42467328  // bf16 [8][200][16384] channel-major

__device__ __forceinline__ float bf2f(u16 x){ u32 u=((u32)x)<<16; float f; __builtin_memcpy(&f,&u,4); return f; }
__device__ __forceinline__ u16 f2bf(float f){ u32 u; __builtin_memcpy(&u,&f,4); return (u16)((u + 0x7fffu + ((u>>16)&1u))>>16); }
__device__ __forceinline__ float lrelu(float x){ return x>0.f ? x : 0.01f*x; }

template<int M> __device__ __forceinline__ u16 ldb(const void* p, size_t i){
    if (M==1) return ((const u16*)p)[i];
    return f2bf(((const float*)p)[i]);
}
template<int M> __device__ __forceinline__ float ldf(const void* p, size_t i){
    if (M==1) return bf2f(((const u16*)p)[i]);
    return ((const float*)p)[i];
}
// 8 consecutive pixels of one channel -> bf16x8
template<int M> __device__ __forceinline__ short8 ld8(const void* p, size_t i){
    short8 v;
    if (M==1){ __builtin_memcpy(&v, (const u16*)p + i, 16); }
    else {
        float a[8]; __builtin_memcpy(a, (const float*)p + i, 32);
#pragma unroll
        for (int r=0;r<8;r++) v[r] = (short)f2bf(a[r]);
    }
    return v;
}
// swizzled A-tile store: stride in u16 units, chunk XOR to decorrelate banks
__device__ __forceinline__ void stA(u16* At, int stride, int p, int c, u16 v){
    At[p*stride + ((((c>>3) ^ ((p>>1)&7)))<<3) + (c&7)] = v;
}

// ---------------- dtype detector ----------------
__global__ void detect_kernel(const void* __restrict__ emb, u32* __restrict__ flag){
    int tid = threadIdx.x;
    const u16* p = (const u16*)emb;
    int e = (p[tid*2] >> 7) & 0xFF;
    u64 m = __ballot(e >= 100 && e <= 140);
    if (tid == 0) *flag = (__popcll(m) >= 32) ? 1u : 0u;
}

// ---------------- prep ----------------
template<int M>
__global__ __launch_bounds__(256) void k_prep(
    const void* rw, const void* rb, const void* c1w, const void* c1b,
    const void* c2w, const void* c2b, const void* ew, const void* eb,
    const void* ow, const void* ob, const void* gam, const void* bet,
    const void* mn, const void* vr, char* ws, const u32* flag)
{
    if (*flag != (u32)M) return;
    float* wf = (float*)ws;
    int i = blockIdx.x*256 + threadIdx.x;
    if (i < 32768)       ((u16*)(ws+RWB_OFF))[i] = ldb<M>(rw, i);
    else if (i < 36864)  ((u16*)(ws+C1B_OFF))[i-32768] = ldb<M>(c1w, i-32768);
    else if (i < 45056)  ((u16*)(ws+EMBB_OFF))[i-36864] = ldb<M>(ew, i-36864);
    else if (i < 53248)  ((u16*)(ws+OUTB_OFF))[i-45056] = ldb<M>(ow, i-45056);
    else if (i < 126976) {
        int j = i-53248; int o = j/288, k = j - o*288;
        int tap = k>>5, ic = k&31;
        u16 v = 0;
        if (o < 200) v = ldb<M>(c2w, (size_t)o*288 + ic*9 + tap);
        ((u16*)(ws+C2PB_OFF))[j] = v;
    }
    else if (i < 127584) {
        int j = i-126976;
        if (j < 128) wf[RED_B+j] = ldf<M>(rb, j);
        else if (j < 160) wf[C1E_B+j-128] = ldf<M>(c1b, j-128) + ldf<M>(eb, j-128);
        else if (j < 416) { int o = j-160; wf[C2_B+o] = (o<200) ? ldf<M>(c2b,o) : 0.f; }
        else if (j < 480) wf[OUT_B+j-416] = ldf<M>(ob, j-416);
        else if (j < 544) { int c=j-480; wf[BN_SC+c] = ldf<M>(gam,c) * rsqrtf(ldf<M>(vr,c)+1e-5f); }
        else { int c=j-544; wf[BN_SH+c] = ldf<M>(bet,c) - ldf<M>(mn,c)*ldf<M>(gam,c)*rsqrtf(ldf<M>(vr,c)+1e-5f); }
    }
}

// ---------------- reduce: cat2[px][128] = W_red @ concat(ps(hi), lo) ----------------
// grid 2048: one 64-px chunk per block. Lane-per-channel staging, row-uniform LDS stores.
template<int M>
__global__ __launch_bounds__(256) void k_reduce(
    const void* __restrict__ hi, const void* __restrict__ lo,
    const u16* __restrict__ rwB, const float* __restrict__ wf,
    u16* __restrict__ cat2, const u32* __restrict__ flag)
{
    if (*flag != (u32)M) return;
    __shared__ u16 At[64*264];
    const int tid = threadIdx.x, wvi = tid>>6, lane = tid&63;
    const int rt = (wvi>>1)*32, nc0 = (wvi&1)*64;
    const int col = lane&31, q = lane>>5;

    const int gpx = blockIdx.x*64;
    const int b = gpx>>14, p0 = gpx&16383;
    const int h = p0>>7, w0 = p0&127;

    short8 B[2][16];
#pragma unroll
    for (int nt=0; nt<2; nt++){
        int o = nc0 + nt*32 + col;
#pragma unroll
        for (int s=0; s<16; s++)
            __builtin_memcpy(&B[nt][s], rwB + (size_t)o*256 + s*16 + q*8, 16);
    }

    // staging: lanes 0..223 -> lo channel tid; lanes 224..255 -> hi cat-channel tid-224
    if (tid < 224) {
        int c = tid;
        size_t base = ((size_t)(b*224 + c))*HW + p0;
#pragma unroll
        for (int i=0;i<8;i++){
            short8 v = ld8<M>(lo, base + 8*i);
#pragma unroll
            for (int j=0;j<8;j++) stA(At,264, 8*i+j, 32+c, (u16)v[j]);
        }
    } else {
        int cc = tid - 224;
        int hc = cc*4 + (h&1)*2;
        size_t srcE = ((size_t)(b*128 + hc))*4096 + (size_t)(h>>1)*64 + (w0>>1);
#pragma unroll
        for (int i=0;i<4;i++){
            short8 e = ld8<M>(hi, srcE + 8*i);
            short8 o = ld8<M>(hi, srcE + 4096 + 8*i);
#pragma unroll
            for (int j=0;j<8;j++){
                stA(At,264, 16*i+2*j,   cc, (u16)e[j]);
                stA(At,264, 16*i+2*j+1, cc, (u16)o[j]);
            }
        }
    }
    __syncthreads();

    f32x16 acc0, acc1;
#pragma unroll
    for (int r=0;r<16;r++){ acc0[r]=0.f; acc1[r]=0.f; }
    int pp = rt + col, sw = (pp>>1)&7;
    const u16* arow = At + pp*264;
#pragma unroll
    for (int s=0;s<16;s++){
        short8 a;
        __builtin_memcpy(&a, arow + (((2*s+q)^sw)<<3), 16);
        acc0 = __builtin_amdgcn_mfma_f32_32x32x16_bf16(a, B[0][s], acc0, 0,0,0);
        acc1 = __builtin_amdgcn_mfma_f32_32x32x16_bf16(a, B[1][s], acc1, 0,0,0);
    }
#pragma unroll
    for (int nt=0; nt<2; nt++){
        int oc = nc0 + nt*32 + col;
        float bias = wf[RED_B + oc];
#pragma unroll
        for (int r=0;r<16;r++){
            int row = (r&3) + 8*(r>>2) + 4*q;
            float v = (nt ? acc1[r] : acc0[r]) + bias;
            cat2[((size_t)(gpx + rt + row))*128 + oc] = f2bf(v);
        }
    }
}

// ---------------- mix[px][32] = lrelu(conv1(cat2) + embconv(emb)) ----------------
// grid 1024: one 128-px chunk per block.
template<int M>
__global__ __launch_bounds__(256) void k_mix(
    const u16* __restrict__ cat2, const void* __restrict__ emb,
    const u16* __restrict__ c1B, const u16* __restrict__ embB,
    const float* __restrict__ wf, u16* __restrict__ mixt, const u32* __restrict__ flag)
{
    if (*flag != (u32)M) return;
    __shared__ u16 At[128*136];
    const int tid = threadIdx.x, wvi = tid>>6, lane = tid&63;
    const int rt = wvi*32, col = lane&31, q = lane>>5;

    const int gpx = blockIdx.x*128;
    const int b = gpx>>14, p0 = gpx&16383;

    short8 Bc[8];
#pragma unroll
    for (int s=0;s<8;s++)  __builtin_memcpy(&Bc[s], c1B + (size_t)col*128 + s*16 + q*8, 16);

    f32x16 acc;
#pragma unroll
    for (int r=0;r<16;r++) acc[r]=0.f;
    int pp = rt + col, sw = (pp>>1)&7;
    const u16* arow = At + pp*136;

    // phase 0: cat2 (pixel-major vector copy)
#pragma unroll
    for (int i=0;i<8;i++){
        int idx = tid + i*256;
        int p = idx>>4, c16 = idx&15;
        short8 v;
        __builtin_memcpy(&v, cat2 + ((size_t)(gpx+p))*128 + c16*8, 16);
        *(short8*)(At + p*136 + ((c16 ^ ((p>>1)&7))<<3)) = v;
    }
    __syncthreads();
#pragma unroll
    for (int s=0;s<8;s++){
        short8 a; __builtin_memcpy(&a, arow + (((2*s+q)^sw)<<3), 16);
        acc = __builtin_amdgcn_mfma_f32_32x32x16_bf16(a, Bc[s], acc, 0,0,0);
    }

    // phases 1,2: emb halves — lane-per-channel staging, row-uniform stores
    const int chalf = (wvi&1)*64, pxh = (wvi>>1)*64;
#pragma unroll 1
    for (int half=0; half<2; half++){
        short8 Be[8];
#pragma unroll
        for (int s=0;s<8;s++)
            __builtin_memcpy(&Be[s], embB + (size_t)col*256 + half*128 + s*16 + q*8, 16);
        __syncthreads();
        {
            int c = half*128 + chalf + lane;       // global emb channel
            int cl = chalf + lane;                 // local 0..127
            size_t base = ((size_t)(b*256 + c))*HW + p0 + pxh;
#pragma unroll
            for (int i=0;i<8;i++){
                short8 v = ld8<M>(emb, base + 8*i);
#pragma unroll
                for (int j=0;j<8;j++) stA(At,136, pxh+8*i+j, cl, (u16)v[j]);
            }
        }
        __syncthreads();
#pragma unroll
        for (int s=0;s<8;s++){
            short8 a; __builtin_memcpy(&a, arow + (((2*s+q)^sw)<<3), 16);
            acc = __builtin_amdgcn_mfma_f32_32x32x16_bf16(a, Be[s], acc, 0,0,0);
        }
    }
    float bias = wf[C1E_B + col];
#pragma unroll
    for (int r=0;r<16;r++){
        int row = (r&3) + 8*(r>>2) + 4*q;
        mixt[((size_t)(gpx + rt + row))*32 + col] = f2bf(lrelu(acc[r] + bias));
    }
}

// ---------------- conv2 (3x3, 32->200 pad 256) im2col GEMM K=288 ----------------
__global__ __launch_bounds__(256) void k_conv2(
    const u16* __restrict__ mixt, const u16* __restrict__ c2B,
    const float* __restrict__ wf, u16* __restrict__ wgt)
{
    __shared__ u16 halo[100*32];
    const int tid = threadIdx.x, wvi = tid>>6, lane = tid&63;
    const int rt = (wvi>>1)*32, npair = wvi&1;
    const int nh = blockIdx.x & 1;
    const int nc0 = nh*128 + npair*64;
    const int col = lane&31, q = lane>>5;

    short8 B[2][18];
#pragma unroll
    for (int nt=0; nt<2; nt++){
        int o = nc0 + nt*32 + col;
#pragma unroll
        for (int s=0; s<18; s++)
            __builtin_memcpy(&B[nt][s], c2B + (size_t)o*288 + s*16 + q*8, 16);
    }

    for (int it=0; it<4; it++){
        int tile = (blockIdx.x>>1) + it*512;
        int b = tile>>8, tl = tile&255;
        int ty = tl>>4, tx = tl&15;
        __syncthreads();
#pragma unroll
        for (int i=0;i<2;i++){
            int idx = tid + i*256;
            if (idx < 400){
                int point = idx>>2, cq = idx&3;
                int y = ty*8 + point/10 - 1, x = tx*8 + point%10 - 1;
                short8 v;
                if (y>=0 && y<128 && x>=0 && x<128)
                    __builtin_memcpy(&v, mixt + ((size_t)(b*HW + y*128 + x))*32 + cq*8, 16);
                else { short z = 0; v = (short8){z,z,z,z,z,z,z,z}; }
                *(short8*)(halo + point*32 + cq*8) = v;
            }
        }
        __syncthreads();

        f32x16 acc0, acc1;
#pragma unroll
        for (int r=0;r<16;r++){ acc0[r]=0.f; acc1[r]=0.f; }
        int pp = rt + col, py = pp>>3, px = pp&7;
#pragma unroll
        for (int s=0;s<18;s++){
            int tap = s>>1, ih = s&1;
            int dy = tap/3, dx = tap%3;
            short8 a;
            __builtin_memcpy(&a, halo + ((py+dy)*10 + px+dx)*32 + ih*16 + q*8, 16);
            acc0 = __builtin_amdgcn_mfma_f32_32x32x16_bf16(a, B[0][s], acc0, 0,0,0);
            acc1 = __builtin_amdgcn_mfma_f32_32x32x16_bf16(a, B[1][s], acc1, 0,0,0);
        }
#pragma unroll
        for (int nt=0; nt<2; nt++){
            int oc = nc0 + nt*32 + col;
            if (oc < 200){
                float bias = wf[C2_B + oc];
#pragma unroll
                for (int r=0;r<16;r++){
                    int row = (r&3) + 8*(r>>2) + 4*q;
                    int p2 = rt + row;
                    int y = ty*8 + (p2>>3), x = tx*8 + (p2&7);
                    float v = (nt ? acc1[r] : acc0[r]) + bias;
                    wgt[((size_t)(b*200 + oc))*HW + y*128 + x] = f2bf(v);
                }
            }
        }
    }
}

// ---------------- involution (K=5,g=8) + out conv (MFMA) + BN + lrelu ----------------
template<int M>
__global__ __launch_bounds__(256) void k_inv(
    const u16* __restrict__ cat2, const u16* __restrict__ wgt,
    const u16* __restrict__ outB, const float* __restrict__ wf,
    void* __restrict__ out, const u32* __restrict__ flag)
{
    if (*flag != (u32)M) return;
    __shared__ u16 halo[400*16];
    __shared__ u16 og[256*16];
    const int tid = threadIdx.x, wvi = tid>>6, lane = tid&63;
    const int col = lane&31, q = lane>>5;
    const int b = blockIdx.y, ty = blockIdx.x>>3, tx = blockIdx.x&7;
    const int py = tid>>4, px = tid&15;
    const int h = ty*16 + py, w = tx*16 + px;

    f32x16 acc[2][2];
#pragma unroll
    for (int i=0;i<2;i++)
#pragma unroll
    for (int j=0;j<2;j++)
#pragma unroll
    for (int r=0;r<16;r++) acc[i][j][r] = 0.f;

#pragma unroll 1
    for (int g=0; g<8; g++){
        __syncthreads();
#pragma unroll
        for (int i=0;i<4;i++){
            int idx = tid + i*256;
            if (idx < 800){
                int point = idx>>1, cq = idx&1;
                int y = ty*16 + point/20 - 2, x = tx*16 + point%20 - 2;
                short8 v;
                if (y>=0 && y<128 && x>=0 && x<128)
                    __builtin_memcpy(&v, cat2 + ((size_t)(b*HW + y*128 + x))*128 + g*16 + cq*8, 16);
                else { short z=0; v = (short8){z,z,z,z,z,z,z,z}; }
                *(short8*)(halo + point*16 + cq*8) = v;
            }
        }
        __syncthreads();

        float wvv[25];
#pragma unroll
        for (int t=0;t<25;t++)
            wvv[t] = bf2f(wgt[((size_t)(b*200 + g*25 + t))*HW + h*128 + w]);

        float a16[16];
#pragma unroll
        for (int cc=0;cc<16;cc++) a16[cc]=0.f;
#pragma unroll
        for (int t=0;t<25;t++){
            int dy = t/5, dx = t%5;
            u32 vv[8];
            __builtin_memcpy(vv, halo + ((py+dy)*20 + px+dx)*16, 32);
            float wt = wvv[t];
#pragma unroll
            for (int r=0;r<8;r++){
                u32 u = vv[r];
                u32 ulo = u<<16, uhi = u & 0xffff0000u;
                float x0, x1;
                __builtin_memcpy(&x0,&ulo,4); __builtin_memcpy(&x1,&uhi,4);
                a16[2*r]   += wt*x0;
                a16[2*r+1] += wt*x1;
            }
        }
        u32 pk[8];
#pragma unroll
        for (int r=0;r<8;r++) pk[r] = (u32)f2bf(a16[2*r]) | ((u32)f2bf(a16[2*r+1])<<16);
        __syncthreads();
        __builtin_memcpy(og + tid*16, pk, 32);
        __syncthreads();

        short8 bo0, bo1;
        __builtin_memcpy(&bo0, outB + (size_t)(col)*128      + g*16 + q*8, 16);
        __builtin_memcpy(&bo1, outB + (size_t)(32+col)*128   + g*16 + q*8, 16);
#pragma unroll
        for (int rt2=0; rt2<2; rt2++){
            int prow = (wvi*2 + rt2)*32 + col;
            short8 a; __builtin_memcpy(&a, og + prow*16 + q*8, 16);
            acc[rt2][0] = __builtin_amdgcn_mfma_f32_32x32x16_bf16(a, bo0, acc[rt2][0], 0,0,0);
            acc[rt2][1] = __builtin_amdgcn_mfma_f32_32x32x16_bf16(a, bo1, acc[rt2][1], 0,0,0);
        }
    }
#pragma unroll
    for (int rt2=0; rt2<2; rt2++)
#pragma unroll
    for (int nt=0; nt<2; nt++){
        int oc = nt*32 + col;
        float bias = wf[OUT_B+oc], sc = wf[BN_SC+oc], sh = wf[BN_SH+oc];
#pragma unroll
        for (int r=0;r<16;r++){
            int row = (r&3) + 8*(r>>2) + 4*q;
            int p = (wvi*2 + rt2)*32 + row;
            int yy = ty*16 + (p>>4), xx = tx*16 + (p&15);
            float v = lrelu((acc[rt2][nt][r] + bias)*sc + sh);
            size_t oidx = ((size_t)(b*64 + oc))*HW + yy*128 + xx;
            if (M==1) ((u16*)out)[oidx] = f2bf(v);
            else ((float*)out)[oidx] = v;
        }
    }
}

extern "C" void kernel_launch(void* const* d_in, const int* in_sizes, int n_in,
                              void* d_out, int out_size, void* d_ws, size_t ws_size,
                              hipStream_t stream) {
    const void* hi  = d_in[0];
    const void* lo  = d_in[1];
    const void* emb = d_in[2];
    char* ws = (char*)d_ws;
    float* wf = (float*)ws;
    u32* flag = (u32*)(ws + FLAG_OFF);
    u16* cat2 = (u16*)(ws + CAT2_OFF);
    u16* mixt = (u16*)(ws + MIX_OFF);
    u16* wgt  = (u16*)(ws + WGT_OFF);

    detect_kernel<<<1, 64, 0, stream>>>(emb, flag);

    k_prep<0><<<499,256,0,stream>>>(d_in[3],d_in[4],d_in[5],d_in[6],d_in[7],d_in[8],
        d_in[9],d_in[10],d_in[11],d_in[12],d_in[13],d_in[14],d_in[15],d_in[16], ws, flag);
    k_prep<1><<<499,256,0,stream>>>(d_in[3],d_in[4],d_in[5],d_in[6],d_in[7],d_in[8],
        d_in[9],d_in[10],d_in[11],d_in[12],d_in[13],d_in[14],d_in[15],d_in[16], ws, flag);

    k_reduce<0><<<2048,256,0,stream>>>(hi, lo, (const u16*)(ws+RWB_OFF), wf, cat2, flag);
    k_reduce<1><<<2048,256,0,stream>>>(hi, lo, (const u16*)d_in[3],      wf, cat2, flag);

    k_mix<0><<<1024,256,0,stream>>>(cat2, emb, (const u16*)(ws+C1B_OFF), (const u16*)(ws+EMBB_OFF), wf, mixt, flag);
    k_mix<1><<<1024,256,0,stream>>>(cat2, emb, (const u16*)d_in[5],      (const u16*)d_in[9],       wf, mixt, flag);

    k_conv2<<<1024,256,0,stream>>>(mixt, (const u16*)(ws+C2PB_OFF), wf, wgt);

    k_inv<0><<<dim3(64,8),256,0,stream>>>(cat2, wgt, (const u16*)(ws+OUTB_OFF), wf, d_out, flag);
    k_inv<1><<<dim3(64,8),256,0,stream>>>(cat2, wgt, (const u16*)d_in[11],      wf, d_out, flag);
}